// Round 1
// baseline (274.745 us; speedup 1.0000x reference)
//
#include <hip/hip_runtime.h>
#include <hip/hip_bf16.h>

// LoRA grouped GEMM for MI355X (gfx950).
// Dims fixed by the reference module constants:
#define BSZ     4096
#define HID     2048
#define OUTD    2048
#define NM      3
#define NS      4
#define RMAX    64
#define NVALID  3584
#define INTER_LD 192           // NM * RMAX
#define SUMOUT  (NM * OUTD)    // 6144

typedef __attribute__((ext_vector_type(8))) short short8;
typedef __attribute__((ext_vector_type(4))) float f32x4;

__device__ __forceinline__ int slot_of_row(int r) {
    // slot offsets 0,1024,2560,3328 (SLOT_COUNTS = 1024,1536,768,256)
    return (r < 1024) ? 0 : (r < 2560) ? 1 : (r < 3328) ? 2 : 3;
}

__device__ __forceinline__ unsigned short f2bf(float f) {
    union { __hip_bfloat16 h; unsigned short u; } cv;
    cv.h = __float2bfloat16(f);
    return cv.u;
}

struct Frag { union { short8 v; unsigned short u[8]; }; };

__device__ __forceinline__ short8 cvt8(float4 a, float4 b) {
    Frag f;
    f.u[0] = f2bf(a.x); f.u[1] = f2bf(a.y); f.u[2] = f2bf(a.z); f.u[3] = f2bf(a.w);
    f.u[4] = f2bf(b.x); f.u[5] = f2bf(b.y); f.u[6] = f2bf(b.z); f.u[7] = f2bf(b.w);
    return f.v;
}

// ---------------------------------------------------------------------------
// Kernel 1: zero the output rows of tokens with no adapter (reordered rows
// 3584..4095). 512 blocks, one row each: 6144 f32 = 1536 float4.
// ---------------------------------------------------------------------------
__global__ __launch_bounds__(256) void zerofill_k(const int* __restrict__ sids,
                                                  float* __restrict__ out) {
    const int row = NVALID + blockIdx.x;
    const int tok = sids[row];
    float* op = out + (size_t)tok * SUMOUT;
    const int t = threadIdx.x;
    float4 z; z.x = 0.f; z.y = 0.f; z.z = 0.f; z.w = 0.f;
#pragma unroll
    for (int i = 0; i < 6; ++i)
        *reinterpret_cast<float4*>(op + (size_t)(i * 256 + t) * 4) = z;
}

// ---------------------------------------------------------------------------
// Kernel 2: GEMM1  inter[b][m*64+r] = sum_h x[sorted_ids[b]][h] * A[m,s,r,h]
// Grid: 224 blocks = 112 rowblocks(32 rows) x 2 col-halves(96 of 192 cols).
// Block: 4 waves in 2x2 (wave = 16 rows x 48 cols). MFMA 16x16x32 bf16,
// fragments loaded directly from global (both operands K-contiguous).
// Column-frags with r >= slot_rank are skipped entirely (never read later).
// ---------------------------------------------------------------------------
__global__ __launch_bounds__(256) void gemm1_k(const float* __restrict__ x,
                                               const float* __restrict__ A,
                                               const int* __restrict__ sids,
                                               const int* __restrict__ slot_ranks,
                                               unsigned short* __restrict__ inter) {
    const int bid = blockIdx.x;
    const int rb  = bid >> 1;
    const int ch  = bid & 1;
    const int r0  = rb * 32;
    const int s   = slot_of_row(r0);
    const int rank = slot_ranks[s];

    const int t    = threadIdx.x;
    const int w    = t >> 6;
    const int lane = t & 63;
    const int wr   = w >> 1;           // 0..1 : 16-row group
    const int wc   = w & 1;            // 0..1 : 48-col group
    const int r16  = lane & 15;
    const int kg   = lane >> 4;

    const int rowbase = r0 + wr * 16;
    const int colbase = ch * 96 + wc * 48;

    const int tok = sids[rowbase + r16];
    const float* xp = x + (size_t)tok * HID;

    const float* wp[3];
    bool nact[3];
#pragma unroll
    for (int ni = 0; ni < 3; ++ni) {
        const int c = colbase + ni * 16 + r16;
        const int m = c >> 6;
        const int r = c & 63;
        wp[ni] = A + (size_t)((m * NS + s) * RMAX + r) * HID;
        nact[ni] = ((colbase + ni * 16) & 63) < rank;  // frag r-base vs rank
    }

    f32x4 acc[3] = {};

    for (int ks = 0; ks < HID / 32; ++ks) {
        const int kidx = ks * 32 + kg * 8;
        const float4 a0 = *reinterpret_cast<const float4*>(xp + kidx);
        const float4 a1 = *reinterpret_cast<const float4*>(xp + kidx + 4);
        const short8 af = cvt8(a0, a1);
#pragma unroll
        for (int ni = 0; ni < 3; ++ni) {
            if (!nact[ni]) continue;
            const float4 b0 = *reinterpret_cast<const float4*>(wp[ni] + kidx);
            const float4 b1 = *reinterpret_cast<const float4*>(wp[ni] + kidx + 4);
            const short8 bf = cvt8(b0, b1);
            acc[ni] = __builtin_amdgcn_mfma_f32_16x16x32_bf16(af, bf, acc[ni], 0, 0, 0);
        }
    }

    // Epilogue: D layout col = lane&15, row = (lane>>4)*4 + j  (m89-verified)
#pragma unroll
    for (int ni = 0; ni < 3; ++ni) {
        if (!nact[ni]) continue;
        const int col = colbase + ni * 16 + r16;
#pragma unroll
        for (int j = 0; j < 4; ++j) {
            const int row = rowbase + kg * 4 + j;
            inter[(size_t)row * INTER_LD + col] = f2bf(acc[ni][j]);
        }
    }
}

// ---------------------------------------------------------------------------
// Kernel 3: GEMM2  out[tok][m*2048+o] = sum_{r<rank} inter[b][m*64+r]*B[m,s,r,o]
// Grid: 1344 = 56 rowblocks(64) x 3 modules x 8 n-tiles(256).
// Block: 4 waves, wave = 64 rows x 64 cols (mi 0..3, ni 0..3), K = 64 (2 MFMA
// k-steps). a-frags (inter, bf16) are ushort8 loads; b-frags are 8 strided f32
// scalar loads + bf16 convert. Rank mask zeroes a-frag k-groups >= rank.
// ---------------------------------------------------------------------------
__global__ __launch_bounds__(256) void gemm2_k(const unsigned short* __restrict__ inter,
                                               const float* __restrict__ B,
                                               const int* __restrict__ sids,
                                               const int* __restrict__ slot_ranks,
                                               float* __restrict__ out) {
    const int bid = blockIdx.x;
    const int rb  = bid / 24;
    const int rem = bid - rb * 24;
    const int m   = rem >> 3;
    const int nt  = rem & 7;
    const int r0  = rb * 64;
    const int s   = slot_of_row(r0);
    const int rank = slot_ranks[s];

    __shared__ int sid_s[64];
    const int t = threadIdx.x;
    if (t < 64) sid_s[t] = sids[r0 + t];
    __syncthreads();

    const int w    = t >> 6;
    const int lane = t & 63;
    const int r16  = lane & 15;
    const int kg   = lane >> 4;
    const int n0   = nt * 256 + w * 64;

    const float* Bp = B + (size_t)((m * NS + s) * RMAX) * OUTD;

    f32x4 acc[4][4] = {};

#pragma unroll
    for (int kk = 0; kk < 2; ++kk) {
        if (kk * 32 < rank) {
            const int kb = kk * 32 + kg * 8;
            const bool kact = kb < rank;
            short8 af[4];
#pragma unroll
            for (int mi = 0; mi < 4; ++mi) {
                if (kact) {
                    af[mi] = *reinterpret_cast<const short8*>(
                        inter + (size_t)(r0 + mi * 16 + r16) * INTER_LD + m * RMAX + kb);
                } else {
                    short8 z = {0, 0, 0, 0, 0, 0, 0, 0};
                    af[mi] = z;
                }
            }
#pragma unroll
            for (int ni = 0; ni < 4; ++ni) {
                Frag fb;
                const float* bp = Bp + (size_t)kb * OUTD + (n0 + ni * 16 + r16);
#pragma unroll
                for (int j = 0; j < 8; ++j)
                    fb.u[j] = f2bf(bp[(size_t)j * OUTD]);
#pragma unroll
                for (int mi = 0; mi < 4; ++mi)
                    acc[mi][ni] = __builtin_amdgcn_mfma_f32_16x16x32_bf16(
                        af[mi], fb.v, acc[mi][ni], 0, 0, 0);
            }
        }
    }

    // Epilogue: scatter rows to token order; 16 lanes write 64B contiguous.
#pragma unroll
    for (int mi = 0; mi < 4; ++mi) {
#pragma unroll
        for (int j = 0; j < 4; ++j) {
            const int row = mi * 16 + kg * 4 + j;
            const int tok = sid_s[row];
            float* op = out + (size_t)tok * SUMOUT + m * OUTD + n0;
#pragma unroll
            for (int ni = 0; ni < 4; ++ni)
                op[ni * 16 + r16] = acc[mi][ni][j];
        }
    }
}

// ---------------------------------------------------------------------------
extern "C" void kernel_launch(void* const* d_in, const int* in_sizes, int n_in,
                              void* d_out, int out_size, void* d_ws, size_t ws_size,
                              hipStream_t stream) {
    const float* x    = (const float*)d_in[0];
    const float* A    = (const float*)d_in[1];
    const float* B    = (const float*)d_in[2];
    const int* sids   = (const int*)d_in[3];
    // d_in[4] = row_slot (unused; slot boundaries are reference constants)
    const int* ranks  = (const int*)d_in[5];
    float* out        = (float*)d_out;
    unsigned short* inter = (unsigned short*)d_ws;   // [3584][192] bf16 = 1.38 MB

    zerofill_k<<<dim3(BSZ - NVALID), dim3(256), 0, stream>>>(sids, out);
    gemm1_k<<<dim3(224), dim3(256), 0, stream>>>(x, A, sids, ranks, inter);
    gemm2_k<<<dim3(1344), dim3(256), 0, stream>>>(inter, B, sids, ranks, out);
}

// Round 3
// 200.788 us; speedup vs baseline: 1.3683x; 1.3683x over previous
//
#include <hip/hip_runtime.h>
#include <hip/hip_bf16.h>

// LoRA grouped GEMM for MI355X (gfx950).
#define BSZ     4096
#define HID     2048
#define OUTD    2048
#define NM      3
#define NS      4
#define RMAX    64
#define NVALID  3584
#define INTER_LD 192           // NM * RMAX
#define SUMOUT  (NM * OUTD)    // 6144
#define KSPLIT  4
#define KCH     (HID / KSPLIT) // 512

typedef __attribute__((ext_vector_type(8))) short short8;
typedef __attribute__((ext_vector_type(4))) float f32x4;

__device__ __forceinline__ int slot_of_row(int r) {
    // slot offsets 0,1024,2560,3328 (SLOT_COUNTS = 1024,1536,768,256)
    return (r < 1024) ? 0 : (r < 2560) ? 1 : (r < 3328) ? 2 : 3;
}

__device__ __forceinline__ unsigned short f2bf(float f) {
    union { __hip_bfloat16 h; unsigned short u; } cv;
    cv.h = __float2bfloat16(f);
    return cv.u;
}

struct Frag { union { short8 v; unsigned short u[8]; }; };

__device__ __forceinline__ short8 cvt8(float4 a, float4 b) {
    Frag f;
    f.u[0] = f2bf(a.x); f.u[1] = f2bf(a.y); f.u[2] = f2bf(a.z); f.u[3] = f2bf(a.w);
    f.u[4] = f2bf(b.x); f.u[5] = f2bf(b.y); f.u[6] = f2bf(b.z); f.u[7] = f2bf(b.w);
    return f.v;
}

// ---------------------------------------------------------------------------
// Kernel 1: zero the output rows of tokens with no adapter (reordered rows
// 3584..4095). 512 blocks, one row each: 6144 f32 = 1536 float4.
// ---------------------------------------------------------------------------
__global__ __launch_bounds__(256) void zerofill_k(const int* __restrict__ sids,
                                                  float* __restrict__ out) {
    const int row = NVALID + blockIdx.x;
    const int tok = sids[row];
    float* op = out + (size_t)tok * SUMOUT;
    const int t = threadIdx.x;
    float4 z; z.x = 0.f; z.y = 0.f; z.z = 0.f; z.w = 0.f;
#pragma unroll
    for (int i = 0; i < 6; ++i)
        *reinterpret_cast<float4*>(op + (size_t)(i * 256 + t) * 4) = z;
}

// ---------------------------------------------------------------------------
// Kernel 2: transpose+convert B[m][s][k][n] f32 -> Bt[ms][n][k] bf16.
// Grid 96 = 12 ms-slices x 8 n-tiles(256). Each thread owns one n-column:
// 64 coalesced f32 loads (stride OUTD across k), 64 in flight, then 8
// short8 contiguous stores. 6.3 MB read + 3.15 MB write.
// ---------------------------------------------------------------------------
__global__ __launch_bounds__(256) void btrans_k(const float* __restrict__ B,
                                                unsigned short* __restrict__ Bt) {
    const int bid = blockIdx.x;
    const int ms = bid >> 3;
    const int n = ((bid & 7) << 8) + threadIdx.x;
    const float* bp = B + (size_t)ms * RMAX * OUTD + n;
    alignas(16) unsigned short row[RMAX];
#pragma unroll
    for (int k = 0; k < RMAX; ++k) row[k] = f2bf(bp[(size_t)k * OUTD]);
    unsigned short* op = Bt + ((size_t)ms * OUTD + n) * RMAX;
#pragma unroll
    for (int i = 0; i < 8; ++i)
        *reinterpret_cast<short8*>(op + i * 8) = *reinterpret_cast<const short8*>(row + i * 8);
}

// ---------------------------------------------------------------------------
// Kernel 3: GEMM1  inter[b][m*64+r] += sum_{h in kchunk} x[sids[b]][h]*A[m,s,r,h]
// Split-K x4 for occupancy: grid 896 = 112 rowblocks(32) x 2 col-halves(96)
// x 4 k-chunks(512). Block: 4 waves 2x2, wave = 16 rows x 48 cols, 16 k-steps.
// f32 atomic accumulation into memset-zeroed inter (rank-masked cols skipped
// entirely -> remain zero, so gemm2 needs no rank mask).
// ---------------------------------------------------------------------------
__global__ __launch_bounds__(256) void gemm1_k(const float* __restrict__ x,
                                               const float* __restrict__ A,
                                               const int* __restrict__ sids,
                                               const int* __restrict__ slot_ranks,
                                               float* __restrict__ inter) {
    const int bid = blockIdx.x;
    const int kc  = bid & (KSPLIT - 1);
    const int rem = bid >> 2;
    const int rb  = rem >> 1;
    const int ch  = rem & 1;
    const int r0  = rb * 32;
    const int s   = slot_of_row(r0);
    const int rank = slot_ranks[s];
    const int k0  = kc * KCH;

    const int t    = threadIdx.x;
    const int w    = t >> 6;
    const int lane = t & 63;
    const int wr   = w >> 1;
    const int wc   = w & 1;
    const int r16  = lane & 15;
    const int kg   = lane >> 4;

    const int rowbase = r0 + wr * 16;
    const int colbase = ch * 96 + wc * 48;

    const int tok = sids[rowbase + r16];
    const float* xp = x + (size_t)tok * HID + k0;

    const float* wp[3];
    bool nact[3];
#pragma unroll
    for (int ni = 0; ni < 3; ++ni) {
        const int c = colbase + ni * 16 + r16;
        const int m = c >> 6;
        const int r = c & 63;
        wp[ni] = A + (size_t)((m * NS + s) * RMAX + r) * HID + k0;
        nact[ni] = ((colbase + ni * 16) & 63) < rank;
    }

    f32x4 acc[3] = {};

#pragma unroll 2
    for (int ks = 0; ks < KCH / 32; ++ks) {
        const int kidx = ks * 32 + kg * 8;
        const float4 a0 = *reinterpret_cast<const float4*>(xp + kidx);
        const float4 a1 = *reinterpret_cast<const float4*>(xp + kidx + 4);
        const short8 af = cvt8(a0, a1);
#pragma unroll
        for (int ni = 0; ni < 3; ++ni) {
            if (!nact[ni]) continue;
            const float4 b0 = *reinterpret_cast<const float4*>(wp[ni] + kidx);
            const float4 b1 = *reinterpret_cast<const float4*>(wp[ni] + kidx + 4);
            const short8 bf = cvt8(b0, b1);
            acc[ni] = __builtin_amdgcn_mfma_f32_16x16x32_bf16(af, bf, acc[ni], 0, 0, 0);
        }
    }

    // Epilogue: D layout col = lane&15, row = (lane>>4)*4 + j
#pragma unroll
    for (int ni = 0; ni < 3; ++ni) {
        if (!nact[ni]) continue;
        const int col = colbase + ni * 16 + r16;
#pragma unroll
        for (int j = 0; j < 4; ++j) {
            const int row = rowbase + kg * 4 + j;
            unsafeAtomicAdd(&inter[(size_t)row * INTER_LD + col], acc[ni][j]);
        }
    }
}

// ---------------------------------------------------------------------------
// Kernel 4: GEMM2  out[tok][m*2048+o] = sum_r inter[b][m*64+r] * B[m,s,r,o]
// Grid: 1344 = 56 rowblocks(64) x 3 modules x 8 n-tiles(256).
// Block: 4 waves, wave = 64 rows x 64 cols, K = 64 (2 MFMA k-steps; second
// skipped when rank<=32). A-frags: two float4 from f32 inter + convert.
// B-frags: one short8 K-contiguous load from pre-transposed bf16 Bt.
// ---------------------------------------------------------------------------
__global__ __launch_bounds__(256) void gemm2_k(const float* __restrict__ inter,
                                               const unsigned short* __restrict__ Bt,
                                               const int* __restrict__ sids,
                                               const int* __restrict__ slot_ranks,
                                               float* __restrict__ out) {
    const int bid = blockIdx.x;
    const int rb  = bid / 24;
    const int rem = bid - rb * 24;
    const int m   = rem >> 3;
    const int nt  = rem & 7;
    const int r0  = rb * 64;
    const int s   = slot_of_row(r0);
    const int rank = slot_ranks[s];
    const int ms  = m * NS + s;

    __shared__ int sid_s[64];
    const int t = threadIdx.x;
    if (t < 64) sid_s[t] = sids[r0 + t];
    __syncthreads();

    const int w    = t >> 6;
    const int lane = t & 63;
    const int r16  = lane & 15;
    const int kg   = lane >> 4;
    const int n0   = nt * 256 + w * 64;

    const unsigned short* Bp = Bt + (size_t)ms * OUTD * RMAX;

    f32x4 acc[4][4] = {};

    const int nkk = (rank > 32) ? 2 : 1;
    for (int kk = 0; kk < nkk; ++kk) {
        const int kb = kk * 32 + kg * 8;
        short8 af[4];
#pragma unroll
        for (int mi = 0; mi < 4; ++mi) {
            const float* ip = inter + (size_t)(r0 + mi * 16 + r16) * INTER_LD + m * RMAX + kb;
            const float4 i0 = *reinterpret_cast<const float4*>(ip);
            const float4 i1 = *reinterpret_cast<const float4*>(ip + 4);
            af[mi] = cvt8(i0, i1);
        }
#pragma unroll
        for (int ni = 0; ni < 4; ++ni) {
            const short8 bf = *reinterpret_cast<const short8*>(
                Bp + (size_t)(n0 + ni * 16 + r16) * RMAX + kb);
#pragma unroll
            for (int mi = 0; mi < 4; ++mi)
                acc[mi][ni] = __builtin_amdgcn_mfma_f32_16x16x32_bf16(
                    af[mi], bf, acc[mi][ni], 0, 0, 0);
        }
    }

    // Epilogue: scatter rows to token order; 16 lanes write 64B contiguous.
#pragma unroll
    for (int mi = 0; mi < 4; ++mi) {
#pragma unroll
        for (int j = 0; j < 4; ++j) {
            const int row = mi * 16 + kg * 4 + j;
            const int tok = sid_s[row];
            float* op = out + (size_t)tok * SUMOUT + m * OUTD + n0;
#pragma unroll
            for (int ni = 0; ni < 4; ++ni)
                op[ni * 16 + r16] = acc[mi][ni][j];
        }
    }
}

// ---------------------------------------------------------------------------
extern "C" void kernel_launch(void* const* d_in, const int* in_sizes, int n_in,
                              void* d_out, int out_size, void* d_ws, size_t ws_size,
                              hipStream_t stream) {
    const float* x    = (const float*)d_in[0];
    const float* A    = (const float*)d_in[1];
    const float* B    = (const float*)d_in[2];
    const int* sids   = (const int*)d_in[3];
    // d_in[4] = row_slot (unused; slot boundaries are reference constants)
    const int* ranks  = (const int*)d_in[5];
    float* out        = (float*)d_out;

    float* inter = (float*)d_ws;                         // [3584][192] f32 = 2.75 MB
    const size_t inter_bytes = (size_t)NVALID * INTER_LD * sizeof(float);
    unsigned short* Btp = (unsigned short*)((char*)d_ws + inter_bytes);  // 3.15 MB

    hipMemsetAsync(inter, 0, inter_bytes, stream);
    zerofill_k<<<dim3(BSZ - NVALID), dim3(256), 0, stream>>>(sids, out);
    btrans_k<<<dim3(96), dim3(256), 0, stream>>>(B, Btp);
    gemm1_k<<<dim3(112 * 2 * KSPLIT), dim3(256), 0, stream>>>(x, A, sids, ranks, inter);
    gemm2_k<<<dim3(1344), dim3(256), 0, stream>>>(inter, Btp, sids, ranks, out);
}

// Round 4
// 196.629 us; speedup vs baseline: 1.3973x; 1.0212x over previous
//
#include <hip/hip_runtime.h>
#include <hip/hip_bf16.h>

// LoRA grouped GEMM for MI355X (gfx950).
#define BSZ     4096
#define HID     2048
#define OUTD    2048
#define NM      3
#define NS      4
#define RMAX    64
#define NVALID  3584
#define INTER_LD 192           // NM * RMAX
#define SUMOUT  (NM * OUTD)    // 6144
#define KSPLIT  8
#define KCH     (HID / KSPLIT) // 256

typedef __attribute__((ext_vector_type(8))) short short8;
typedef __attribute__((ext_vector_type(4))) float f32x4;

__device__ __forceinline__ int slot_of_row(int r) {
    // slot offsets 0,1024,2560,3328 (SLOT_COUNTS = 1024,1536,768,256)
    return (r < 1024) ? 0 : (r < 2560) ? 1 : (r < 3328) ? 2 : 3;
}

__device__ __forceinline__ unsigned short f2bf(float f) {
    union { __hip_bfloat16 h; unsigned short u; } cv;
    cv.h = __float2bfloat16(f);
    return cv.u;
}

struct Frag { union { short8 v; unsigned short u[8]; }; };

__device__ __forceinline__ short8 cvt8(float4 a, float4 b) {
    Frag f;
    f.u[0] = f2bf(a.x); f.u[1] = f2bf(a.y); f.u[2] = f2bf(a.z); f.u[3] = f2bf(a.w);
    f.u[4] = f2bf(b.x); f.u[5] = f2bf(b.y); f.u[6] = f2bf(b.z); f.u[7] = f2bf(b.w);
    return f.v;
}

// ---------------------------------------------------------------------------
// Kernel 1: zero the output rows of tokens with no adapter (reordered rows
// 3584..4095). 512 blocks, one row each: 6144 f32 = 1536 float4.
// ---------------------------------------------------------------------------
__global__ __launch_bounds__(256) void zerofill_k(const int* __restrict__ sids,
                                                  float* __restrict__ out) {
    const int row = NVALID + blockIdx.x;
    const int tok = sids[row];
    float* op = out + (size_t)tok * SUMOUT;
    const int t = threadIdx.x;
    float4 z; z.x = 0.f; z.y = 0.f; z.z = 0.f; z.w = 0.f;
#pragma unroll
    for (int i = 0; i < 6; ++i)
        *reinterpret_cast<float4*>(op + (size_t)(i * 256 + t) * 4) = z;
}

// ---------------------------------------------------------------------------
// Kernel 2: transpose+convert B[m][s][k][n] f32 -> Bt[ms][n][k] bf16.
// Grid 96 = 12 ms-slices x 8 n-tiles(256). Each thread owns one n-column:
// 64 coalesced f32 loads (stride OUTD across k), then 8 short8 stores.
// ---------------------------------------------------------------------------
__global__ __launch_bounds__(256) void btrans_k(const float* __restrict__ B,
                                                unsigned short* __restrict__ Bt) {
    const int bid = blockIdx.x;
    const int ms = bid >> 3;
    const int n = ((bid & 7) << 8) + threadIdx.x;
    const float* bp = B + (size_t)ms * RMAX * OUTD + n;
    alignas(16) unsigned short row[RMAX];
#pragma unroll
    for (int k = 0; k < RMAX; ++k) row[k] = f2bf(bp[(size_t)k * OUTD]);
    unsigned short* op = Bt + ((size_t)ms * OUTD + n) * RMAX;
#pragma unroll
    for (int i = 0; i < 8; ++i)
        *reinterpret_cast<short8*>(op + i * 8) = *reinterpret_cast<const short8*>(row + i * 8);
}

// ---------------------------------------------------------------------------
// Kernel 3: GEMM1  inter[b][m*64+r] += sum_{h in kchunk} x[sids[b]][h]*A[m,s,r,h]
// Split-K x8 for occupancy: grid 1792 = 112 rowblocks(32) x 2 col-halves(96)
// x 8 k-chunks(256). Block: 4 waves 2x2, wave = 16 rows x 48 cols, 8 k-steps.
// f32 atomic accumulation into memset-zeroed inter (rank-masked cols skipped
// entirely -> remain zero, so gemm2 needs no rank mask).
// ---------------------------------------------------------------------------
__global__ __launch_bounds__(256) void gemm1_k(const float* __restrict__ x,
                                               const float* __restrict__ A,
                                               const int* __restrict__ sids,
                                               const int* __restrict__ slot_ranks,
                                               float* __restrict__ inter) {
    const int bid = blockIdx.x;
    const int kc  = bid & (KSPLIT - 1);
    const int rem = bid >> 3;
    const int rb  = rem >> 1;
    const int ch  = rem & 1;
    const int r0  = rb * 32;
    const int s   = slot_of_row(r0);
    const int rank = slot_ranks[s];
    const int k0  = kc * KCH;

    const int t    = threadIdx.x;
    const int w    = t >> 6;
    const int lane = t & 63;
    const int wr   = w >> 1;
    const int wc   = w & 1;
    const int r16  = lane & 15;
    const int kg   = lane >> 4;

    const int rowbase = r0 + wr * 16;
    const int colbase = ch * 96 + wc * 48;

    const int tok = sids[rowbase + r16];
    const float* xp = x + (size_t)tok * HID + k0;

    const float* wp[3];
    bool nact[3];
#pragma unroll
    for (int ni = 0; ni < 3; ++ni) {
        const int c = colbase + ni * 16 + r16;
        const int m = c >> 6;
        const int r = c & 63;
        wp[ni] = A + (size_t)((m * NS + s) * RMAX + r) * HID + k0;
        nact[ni] = ((colbase + ni * 16) & 63) < rank;
    }

    f32x4 acc[3] = {};

#pragma unroll 2
    for (int ks = 0; ks < KCH / 32; ++ks) {
        const int kidx = ks * 32 + kg * 8;
        const float4 a0 = *reinterpret_cast<const float4*>(xp + kidx);
        const float4 a1 = *reinterpret_cast<const float4*>(xp + kidx + 4);
        const short8 af = cvt8(a0, a1);
#pragma unroll
        for (int ni = 0; ni < 3; ++ni) {
            if (!nact[ni]) continue;
            const float4 b0 = *reinterpret_cast<const float4*>(wp[ni] + kidx);
            const float4 b1 = *reinterpret_cast<const float4*>(wp[ni] + kidx + 4);
            const short8 bf = cvt8(b0, b1);
            acc[ni] = __builtin_amdgcn_mfma_f32_16x16x32_bf16(af, bf, acc[ni], 0, 0, 0);
        }
    }

    // Epilogue: D layout col = lane&15, row = (lane>>4)*4 + j
#pragma unroll
    for (int ni = 0; ni < 3; ++ni) {
        if (!nact[ni]) continue;
        const int col = colbase + ni * 16 + r16;
#pragma unroll
        for (int j = 0; j < 4; ++j) {
            const int row = rowbase + kg * 4 + j;
            unsafeAtomicAdd(&inter[(size_t)row * INTER_LD + col], acc[ni][j]);
        }
    }
}

// ---------------------------------------------------------------------------
// Kernel 4: GEMM2  out[tok][m*2048+o] = sum_r inter[b][m*64+r] * B[m,s,r,o]
// Grid: 1344 = 56 rowblocks(64) x 3 modules x 8 n-tiles(256).
// Block: 4 waves, wave = 64 rows x 64 cols, K = 64 (2 MFMA k-steps; second
// skipped when rank<=32).
// SWAPPED operands: mfma(bf, af) -> D transposed, so each lane holds
// row = r16 (one token row), cols = kg*4+j (4 consecutive) => float4 stores.
// ---------------------------------------------------------------------------
__global__ __launch_bounds__(256) void gemm2_k(const float* __restrict__ inter,
                                               const unsigned short* __restrict__ Bt,
                                               const int* __restrict__ sids,
                                               const int* __restrict__ slot_ranks,
                                               float* __restrict__ out) {
    const int bid = blockIdx.x;
    const int rb  = bid / 24;
    const int rem = bid - rb * 24;
    const int m   = rem >> 3;
    const int nt  = rem & 7;
    const int r0  = rb * 64;
    const int s   = slot_of_row(r0);
    const int rank = slot_ranks[s];
    const int ms  = m * NS + s;

    const int t    = threadIdx.x;
    const int w    = t >> 6;
    const int lane = t & 63;
    const int r16  = lane & 15;
    const int kg   = lane >> 4;
    const int n0   = nt * 256 + w * 64;

    // Per-lane token ids for the 4 row-frags (register, no LDS needed).
    int tok[4];
#pragma unroll
    for (int mi = 0; mi < 4; ++mi) tok[mi] = sids[r0 + mi * 16 + r16];

    const unsigned short* Bp = Bt + (size_t)ms * OUTD * RMAX;

    f32x4 acc[4][4] = {};

    const int nkk = (rank > 32) ? 2 : 1;
    for (int kk = 0; kk < nkk; ++kk) {
        const int kb = kk * 32 + kg * 8;
        short8 af[4];
#pragma unroll
        for (int mi = 0; mi < 4; ++mi) {
            const float* ip = inter + (size_t)(r0 + mi * 16 + r16) * INTER_LD + m * RMAX + kb;
            const float4 i0 = *reinterpret_cast<const float4*>(ip);
            const float4 i1 = *reinterpret_cast<const float4*>(ip + 4);
            af[mi] = cvt8(i0, i1);
        }
#pragma unroll
        for (int ni = 0; ni < 4; ++ni) {
            const short8 bf = *reinterpret_cast<const short8*>(
                Bp + (size_t)(n0 + ni * 16 + r16) * RMAX + kb);
#pragma unroll
            for (int mi = 0; mi < 4; ++mi)
                acc[mi][ni] = __builtin_amdgcn_mfma_f32_16x16x32_bf16(
                    bf, af[mi], acc[mi][ni], 0, 0, 0);   // swapped: D = tileT
        }
    }

    // Epilogue: lane r16 owns token row tok[mi]; cols n0+ni*16+kg*4..+3.
#pragma unroll
    for (int mi = 0; mi < 4; ++mi) {
        float* op = out + (size_t)tok[mi] * SUMOUT + m * OUTD + n0 + kg * 4;
#pragma unroll
        for (int ni = 0; ni < 4; ++ni) {
            float4 v;
            v.x = acc[mi][ni][0]; v.y = acc[mi][ni][1];
            v.z = acc[mi][ni][2]; v.w = acc[mi][ni][3];
            *reinterpret_cast<float4*>(op + ni * 16) = v;
        }
    }
}

// ---------------------------------------------------------------------------
extern "C" void kernel_launch(void* const* d_in, const int* in_sizes, int n_in,
                              void* d_out, int out_size, void* d_ws, size_t ws_size,
                              hipStream_t stream) {
    const float* x    = (const float*)d_in[0];
    const float* A    = (const float*)d_in[1];
    const float* B    = (const float*)d_in[2];
    const int* sids   = (const int*)d_in[3];
    // d_in[4] = row_slot (unused; slot boundaries are reference constants)
    const int* ranks  = (const int*)d_in[5];
    float* out        = (float*)d_out;

    float* inter = (float*)d_ws;                         // [3584][192] f32 = 2.75 MB
    const size_t inter_bytes = (size_t)NVALID * INTER_LD * sizeof(float);
    unsigned short* Btp = (unsigned short*)((char*)d_ws + inter_bytes);  // 3.15 MB

    hipMemsetAsync(inter, 0, inter_bytes, stream);
    zerofill_k<<<dim3(BSZ - NVALID), dim3(256), 0, stream>>>(sids, out);
    btrans_k<<<dim3(96), dim3(256), 0, stream>>>(B, Btp);
    gemm1_k<<<dim3(112 * 2 * KSPLIT), dim3(256), 0, stream>>>(x, A, sids, ranks, inter);
    gemm2_k<<<dim3(1344), dim3(256), 0, stream>>>(inter, Btp, sids, ranks, out);
}

// Round 9
// 195.125 us; speedup vs baseline: 1.4080x; 1.0077x over previous
//
#include <hip/hip_runtime.h>
#include <hip/hip_bf16.h>

// LoRA grouped GEMM for MI355X (gfx950).
#define BSZ     4096
#define HID     2048
#define OUTD    2048
#define NM      3
#define NS      4
#define RMAX    64
#define NVALID  3584
#define INTER_LD 192           // NM * RMAX
#define SUMOUT  (NM * OUTD)    // 6144
#define KSPLIT  8
#define KCH     (HID / KSPLIT) // 256
#define INTER_ELEMS (NVALID * INTER_LD)   // 688128

typedef __attribute__((ext_vector_type(8))) short short8;
typedef __attribute__((ext_vector_type(4))) float f32x4;

__device__ __forceinline__ int slot_of_row(int r) {
    // slot offsets 0,1024,2560,3328 (SLOT_COUNTS = 1024,1536,768,256)
    return (r < 1024) ? 0 : (r < 2560) ? 1 : (r < 3328) ? 2 : 3;
}

__device__ __forceinline__ unsigned short f2bf(float f) {
    union { __hip_bfloat16 h; unsigned short u; } cv;
    cv.h = __float2bfloat16(f);
    return cv.u;
}

struct Frag { union { short8 v; unsigned short u[8]; }; };

__device__ __forceinline__ short8 cvt8(float4 a, float4 b) {
    Frag f;
    f.u[0] = f2bf(a.x); f.u[1] = f2bf(a.y); f.u[2] = f2bf(a.z); f.u[3] = f2bf(a.w);
    f.u[4] = f2bf(b.x); f.u[5] = f2bf(b.y); f.u[6] = f2bf(b.z); f.u[7] = f2bf(b.w);
    return f.v;
}

// ---------------------------------------------------------------------------
// Kernel 1: zero output rows of tokens with no adapter (reordered 3584..4095).
// ---------------------------------------------------------------------------
__global__ __launch_bounds__(256) void zerofill_k(const int* __restrict__ sids,
                                                  float* __restrict__ out) {
    const int row = NVALID + blockIdx.x;
    const int tok = sids[row];
    float* op = out + (size_t)tok * SUMOUT;
    const int t = threadIdx.x;
    float4 z; z.x = 0.f; z.y = 0.f; z.z = 0.f; z.w = 0.f;
#pragma unroll
    for (int i = 0; i < 6; ++i)
        *reinterpret_cast<float4*>(op + (size_t)(i * 256 + t) * 4) = z;
}

// ---------------------------------------------------------------------------
// Kernel 2: gather + convert x -> xg[b][h] bf16 (sorted token order).
// Grid 896 x 4 rows; each thread converts one short8 (8 f32 reads, coalesced).
// ---------------------------------------------------------------------------
__global__ __launch_bounds__(256) void xgather_k(const float* __restrict__ x,
                                                 const int* __restrict__ sids,
                                                 unsigned short* __restrict__ xg) {
    const int t = threadIdx.x;
#pragma unroll
    for (int i = 0; i < 4; ++i) {
        const int row = blockIdx.x * 4 + i;
        const int tok = sids[row];
        const float* xp = x + (size_t)tok * HID + t * 8;
        const float4 a = *reinterpret_cast<const float4*>(xp);
        const float4 b = *reinterpret_cast<const float4*>(xp + 4);
        *reinterpret_cast<short8*>(xg + (size_t)row * HID + t * 8) = cvt8(a, b);
    }
}

// ---------------------------------------------------------------------------
// Kernel 3: convert A (f32, already [ms][r][h] K-contiguous) -> At bf16.
// 1.57M elems / 8 per thread = 196608 threads = 768 blocks.
// ---------------------------------------------------------------------------
__global__ __launch_bounds__(256) void aconv_k(const float* __restrict__ A,
                                               unsigned short* __restrict__ At) {
    const size_t idx = ((size_t)blockIdx.x * 256 + threadIdx.x) * 8;
    const float4 a = *reinterpret_cast<const float4*>(A + idx);
    const float4 b = *reinterpret_cast<const float4*>(A + idx + 4);
    *reinterpret_cast<short8*>(At + idx) = cvt8(a, b);
}

// ---------------------------------------------------------------------------
// Kernel 4: transpose+convert B[ms][k][n] f32 -> Bt[ms][n][k] bf16.
// ---------------------------------------------------------------------------
__global__ __launch_bounds__(256) void btrans_k(const float* __restrict__ B,
                                                unsigned short* __restrict__ Bt) {
    const int bid = blockIdx.x;
    const int ms = bid >> 3;
    const int n = ((bid & 7) << 8) + threadIdx.x;
    const float* bp = B + (size_t)ms * RMAX * OUTD + n;
    alignas(16) unsigned short row[RMAX];
#pragma unroll
    for (int k = 0; k < RMAX; ++k) row[k] = f2bf(bp[(size_t)k * OUTD]);
    unsigned short* op = Bt + ((size_t)ms * OUTD + n) * RMAX;
#pragma unroll
    for (int i = 0; i < 8; ++i)
        *reinterpret_cast<short8*>(op + i * 8) = *reinterpret_cast<const short8*>(row + i * 8);
}

// ---------------------------------------------------------------------------
// Kernel 5: GEMM1  inter8[kc][b][m*64+r] = sum_{h in kchunk} xg[b][h]*At[ms][r][h]
// Grid 1792 = 112 rowblocks(32) x 2 col-halves(96) x 8 k-chunks(256).
// Block: 4 waves 2x2, wave = 16 rows x 48 cols, 8 k-steps, all-bf16 short8
// loads (no VALU converts). Plain stores to private slice (no atomics);
// rank-masked frags store their zero-init acc so downstream needs no mask.
// ---------------------------------------------------------------------------
__global__ __launch_bounds__(256) void gemm1_k(const unsigned short* __restrict__ xg,
                                               const unsigned short* __restrict__ At,
                                               const int* __restrict__ slot_ranks,
                                               float* __restrict__ inter8) {
    const int bid = blockIdx.x;
    const int kc  = bid & (KSPLIT - 1);
    const int rem = bid >> 3;
    const int rb  = rem >> 1;
    const int ch  = rem & 1;
    const int r0  = rb * 32;
    const int s   = slot_of_row(r0);
    const int rank = slot_ranks[s];
    const int k0  = kc * KCH;

    const int t    = threadIdx.x;
    const int w    = t >> 6;
    const int lane = t & 63;
    const int wr   = w >> 1;
    const int wc   = w & 1;
    const int r16  = lane & 15;
    const int kg   = lane >> 4;

    const int rowbase = r0 + wr * 16;
    const int colbase = ch * 96 + wc * 48;

    const unsigned short* xp = xg + (size_t)(rowbase + r16) * HID + k0 + kg * 8;

    const unsigned short* wp[3];
    bool nact[3];
#pragma unroll
    for (int ni = 0; ni < 3; ++ni) {
        const int c = colbase + ni * 16 + r16;
        const int m = c >> 6;
        const int r = c & 63;
        wp[ni] = At + (size_t)((m * NS + s) * RMAX + r) * HID + k0 + kg * 8;
        nact[ni] = ((colbase + ni * 16) & 63) < rank;
    }

    f32x4 acc[3] = {};

#pragma unroll
    for (int ks = 0; ks < KCH / 32; ++ks) {
        const int kidx = ks * 32;
        const short8 af = *reinterpret_cast<const short8*>(xp + kidx);
#pragma unroll
        for (int ni = 0; ni < 3; ++ni) {
            if (!nact[ni]) continue;
            const short8 bf = *reinterpret_cast<const short8*>(wp[ni] + kidx);
            acc[ni] = __builtin_amdgcn_mfma_f32_16x16x32_bf16(af, bf, acc[ni], 0, 0, 0);
        }
    }

    // Epilogue: D layout col = lane&15, row = (lane>>4)*4 + j. Unconditional
    // stores (masked frags write zeros).
    float* slice = inter8 + (size_t)kc * INTER_ELEMS;
#pragma unroll
    for (int ni = 0; ni < 3; ++ni) {
        const int col = colbase + ni * 16 + r16;
#pragma unroll
        for (int j = 0; j < 4; ++j) {
            const int row = rowbase + kg * 4 + j;
            slice[(size_t)row * INTER_LD + col] = acc[ni][j];
        }
    }
}

// ---------------------------------------------------------------------------
// Kernel 6: reduce 8 f32 slices -> interb bf16. 672 blocks x 256 threads x
// 4 elems (float4 loads per slice, coalesced).
// ---------------------------------------------------------------------------
__global__ __launch_bounds__(256) void reduce_k(const float* __restrict__ inter8,
                                                unsigned short* __restrict__ interb) {
    const size_t idx = ((size_t)blockIdx.x * 256 + threadIdx.x) * 4;
    f32x4 s = {};
#pragma unroll
    for (int kc = 0; kc < KSPLIT; ++kc) {
        const float4 v = *reinterpret_cast<const float4*>(inter8 + (size_t)kc * INTER_ELEMS + idx);
        s[0] += v.x; s[1] += v.y; s[2] += v.z; s[3] += v.w;
    }
    union { unsigned short u[4]; uint2 d; } o;
#pragma unroll
    for (int j = 0; j < 4; ++j) o.u[j] = f2bf(s[j]);
    *reinterpret_cast<uint2*>(interb + idx) = o.d;
}

// ---------------------------------------------------------------------------
// Kernel 7: GEMM2  out[tok][m*2048+o] = sum_r interb[b][m*64+r] * Bt[ms][o][r]
// Grid: 1344 = 56 rowblocks(64) x 3 modules x 8 n-tiles(256).
// Block: 4 waves, wave = 64 rows x 64 cols, K = 64 (2 MFMA k-steps; second
// skipped when rank<=32). All-bf16 short8 loads.
// SWAPPED operands: mfma(bf, af) -> D transposed; lane holds one token row,
// 4 consecutive n-cols => float4 stores.
// ---------------------------------------------------------------------------
__global__ __launch_bounds__(256) void gemm2_k(const unsigned short* __restrict__ interb,
                                               const unsigned short* __restrict__ Bt,
                                               const int* __restrict__ sids,
                                               const int* __restrict__ slot_ranks,
                                               float* __restrict__ out) {
    const int bid = blockIdx.x;
    const int rb  = bid / 24;
    const int rem = bid - rb * 24;
    const int m   = rem >> 3;
    const int nt  = rem & 7;
    const int r0  = rb * 64;
    const int s   = slot_of_row(r0);
    const int rank = slot_ranks[s];
    const int ms  = m * NS + s;

    const int t    = threadIdx.x;
    const int w    = t >> 6;
    const int lane = t & 63;
    const int r16  = lane & 15;
    const int kg   = lane >> 4;
    const int n0   = nt * 256 + w * 64;

    int tok[4];
#pragma unroll
    for (int mi = 0; mi < 4; ++mi) tok[mi] = sids[r0 + mi * 16 + r16];

    const unsigned short* Bp = Bt + (size_t)ms * OUTD * RMAX;

    f32x4 acc[4][4] = {};

    const int nkk = (rank > 32) ? 2 : 1;
    for (int kk = 0; kk < nkk; ++kk) {
        const int kb = kk * 32 + kg * 8;
        short8 af[4];
#pragma unroll
        for (int mi = 0; mi < 4; ++mi)
            af[mi] = *reinterpret_cast<const short8*>(
                interb + (size_t)(r0 + mi * 16 + r16) * INTER_LD + m * RMAX + kb);
#pragma unroll
        for (int ni = 0; ni < 4; ++ni) {
            const short8 bf = *reinterpret_cast<const short8*>(
                Bp + (size_t)(n0 + ni * 16 + r16) * RMAX + kb);
#pragma unroll
            for (int mi = 0; mi < 4; ++mi)
                acc[mi][ni] = __builtin_amdgcn_mfma_f32_16x16x32_bf16(
                    bf, af[mi], acc[mi][ni], 0, 0, 0);   // swapped: D = tileT
        }
    }

    // Epilogue: lane r16 owns token row tok[mi]; cols n0+ni*16+kg*4..+3.
#pragma unroll
    for (int mi = 0; mi < 4; ++mi) {
        float* op = out + (size_t)tok[mi] * SUMOUT + m * OUTD + n0 + kg * 4;
#pragma unroll
        for (int ni = 0; ni < 4; ++ni) {
            float4 v;
            v.x = acc[mi][ni][0]; v.y = acc[mi][ni][1];
            v.z = acc[mi][ni][2]; v.w = acc[mi][ni][3];
            *reinterpret_cast<float4*>(op + ni * 16) = v;
        }
    }
}

// ---------------------------------------------------------------------------
extern "C" void kernel_launch(void* const* d_in, const int* in_sizes, int n_in,
                              void* d_out, int out_size, void* d_ws, size_t ws_size,
                              hipStream_t stream) {
    const float* x    = (const float*)d_in[0];
    const float* A    = (const float*)d_in[1];
    const float* B    = (const float*)d_in[2];
    const int* sids   = (const int*)d_in[3];
    // d_in[4] = row_slot (unused; slot boundaries are reference constants)
    const int* ranks  = (const int*)d_in[5];
    float* out        = (float*)d_out;

    char* ws = (char*)d_ws;
    float* inter8 = (float*)ws;                                   // 22.02 MB
    size_t off = (size_t)KSPLIT * INTER_ELEMS * sizeof(float);
    unsigned short* interb = (unsigned short*)(ws + off);         // 1.38 MB
    off += (size_t)INTER_ELEMS * sizeof(unsigned short);
    unsigned short* xg = (unsigned short*)(ws + off);             // 14.68 MB
    off += (size_t)NVALID * HID * sizeof(unsigned short);
    unsigned short* At = (unsigned short*)(ws + off);             // 3.15 MB
    off += (size_t)NM * NS * RMAX * HID * sizeof(unsigned short);
    unsigned short* Btp = (unsigned short*)(ws + off);            // 3.15 MB

    zerofill_k<<<dim3(BSZ - NVALID), dim3(256), 0, stream>>>(sids, out);
    xgather_k<<<dim3(NVALID / 4), dim3(256), 0, stream>>>(x, sids, xg);
    aconv_k<<<dim3(768), dim3(256), 0, stream>>>(A, At);
    btrans_k<<<dim3(96), dim3(256), 0, stream>>>(B, Btp);
    gemm1_k<<<dim3(112 * 2 * KSPLIT), dim3(256), 0, stream>>>(xg, At, ranks, inter8);
    reduce_k<<<dim3(INTER_ELEMS / 1024), dim3(256), 0, stream>>>(inter8, interb);
    gemm2_k<<<dim3(1344), dim3(256), 0, stream>>>(interb, Btp, sids, ranks, out);
}

// Round 12
// 194.485 us; speedup vs baseline: 1.4127x; 1.0033x over previous
//
#include <hip/hip_runtime.h>
#include <hip/hip_bf16.h>

// LoRA grouped GEMM for MI355X (gfx950). 4-launch version:
// prep (fused zerofill+xgather+aconv+btrans) -> gemm1 -> reduce -> gemm2.
#define BSZ     4096
#define HID     2048
#define OUTD    2048
#define NM      3
#define NS      4
#define RMAX    64
#define NVALID  3584
#define INTER_LD 192           // NM * RMAX
#define SUMOUT  (NM * OUTD)    // 6144
#define KSPLIT  8
#define KCH     (HID / KSPLIT) // 256
#define INTER_ELEMS (NVALID * INTER_LD)   // 688128

typedef __attribute__((ext_vector_type(8))) short short8;
typedef __attribute__((ext_vector_type(4))) float f32x4;

__device__ __forceinline__ int slot_of_row(int r) {
    // slot offsets 0,1024,2560,3328 (SLOT_COUNTS = 1024,1536,768,256)
    return (r < 1024) ? 0 : (r < 2560) ? 1 : (r < 3328) ? 2 : 3;
}

__device__ __forceinline__ unsigned short f2bf(float f) {
    union { __hip_bfloat16 h; unsigned short u; } cv;
    cv.h = __float2bfloat16(f);
    return cv.u;
}

struct Frag { union { short8 v; unsigned short u[8]; }; };

__device__ __forceinline__ short8 cvt8(float4 a, float4 b) {
    Frag f;
    f.u[0] = f2bf(a.x); f.u[1] = f2bf(a.y); f.u[2] = f2bf(a.z); f.u[3] = f2bf(a.w);
    f.u[4] = f2bf(b.x); f.u[5] = f2bf(b.y); f.u[6] = f2bf(b.z); f.u[7] = f2bf(b.w);
    return f.v;
}

// ---------------------------------------------------------------------------
// Kernel 1 (FUSED prep): block-range dispatch over 2272 blocks:
//   [0,896)     xgather : gather+convert x -> xg bf16, 4 rows/block
//   [896,1408)  zerofill: zero out rows of tokens with no adapter
//   [1408,2176) aconv   : A f32 -> At bf16 (layout unchanged, K-contiguous)
//   [2176,2272) btrans  : B[ms][k][n] f32 -> Bt[ms][n][k] bf16
// All four are independent; branches are wave-uniform (per-block).
// ---------------------------------------------------------------------------
__global__ __launch_bounds__(256) void prep_k(const float* __restrict__ x,
                                              const int* __restrict__ sids,
                                              const float* __restrict__ A,
                                              const float* __restrict__ B,
                                              unsigned short* __restrict__ xg,
                                              unsigned short* __restrict__ At,
                                              unsigned short* __restrict__ Bt,
                                              float* __restrict__ out) {
    const int bid = blockIdx.x;
    const int t = threadIdx.x;
    if (bid < 896) {
        // ---- xgather: rows 4*bid .. 4*bid+3
#pragma unroll
        for (int i = 0; i < 4; ++i) {
            const int row = bid * 4 + i;
            const int tok = sids[row];
            const float* xp = x + (size_t)tok * HID + t * 8;
            const float4 a = *reinterpret_cast<const float4*>(xp);
            const float4 b = *reinterpret_cast<const float4*>(xp + 4);
            *reinterpret_cast<short8*>(xg + (size_t)row * HID + t * 8) = cvt8(a, b);
        }
    } else if (bid < 1408) {
        // ---- zerofill: reordered row NVALID + (bid-896)
        const int row = NVALID + (bid - 896);
        const int tok = sids[row];
        float* op = out + (size_t)tok * SUMOUT;
        float4 z; z.x = 0.f; z.y = 0.f; z.z = 0.f; z.w = 0.f;
#pragma unroll
        for (int i = 0; i < 6; ++i)
            *reinterpret_cast<float4*>(op + (size_t)(i * 256 + t) * 4) = z;
    } else if (bid < 2176) {
        // ---- aconv: 8 contiguous elems per thread
        const size_t idx = ((size_t)(bid - 1408) * 256 + t) * 8;
        const float4 a = *reinterpret_cast<const float4*>(A + idx);
        const float4 b = *reinterpret_cast<const float4*>(A + idx + 4);
        *reinterpret_cast<short8*>(At + idx) = cvt8(a, b);
    } else {
        // ---- btrans: one n-column of one ms-slice per thread
        const int b2 = bid - 2176;
        const int ms = b2 >> 3;
        const int n = ((b2 & 7) << 8) + t;
        const float* bp = B + (size_t)ms * RMAX * OUTD + n;
        alignas(16) unsigned short row[RMAX];
#pragma unroll
        for (int k = 0; k < RMAX; ++k) row[k] = f2bf(bp[(size_t)k * OUTD]);
        unsigned short* op = Bt + ((size_t)ms * OUTD + n) * RMAX;
#pragma unroll
        for (int i = 0; i < 8; ++i)
            *reinterpret_cast<short8*>(op + i * 8) = *reinterpret_cast<const short8*>(row + i * 8);
    }
}

// ---------------------------------------------------------------------------
// Kernel 2: GEMM1  inter8[kc][b][m*64+r] = sum_{h in kchunk} xg[b][h]*At[ms][r][h]
// Grid 1792 = 112 rowblocks(32) x 2 col-halves(96) x 8 k-chunks(256).
// Block: 4 waves 2x2, wave = 16 rows x 48 cols, 8 k-steps, all-bf16 short8
// loads. Plain stores to private slice (no atomics); rank-masked frags store
// their zero-init acc so downstream needs no mask.
// ---------------------------------------------------------------------------
__global__ __launch_bounds__(256) void gemm1_k(const unsigned short* __restrict__ xg,
                                               const unsigned short* __restrict__ At,
                                               const int* __restrict__ slot_ranks,
                                               float* __restrict__ inter8) {
    const int bid = blockIdx.x;
    const int kc  = bid & (KSPLIT - 1);
    const int rem = bid >> 3;
    const int rb  = rem >> 1;
    const int ch  = rem & 1;
    const int r0  = rb * 32;
    const int s   = slot_of_row(r0);
    const int rank = slot_ranks[s];
    const int k0  = kc * KCH;

    const int t    = threadIdx.x;
    const int w    = t >> 6;
    const int lane = t & 63;
    const int wr   = w >> 1;
    const int wc   = w & 1;
    const int r16  = lane & 15;
    const int kg   = lane >> 4;

    const int rowbase = r0 + wr * 16;
    const int colbase = ch * 96 + wc * 48;

    const unsigned short* xp = xg + (size_t)(rowbase + r16) * HID + k0 + kg * 8;

    const unsigned short* wp[3];
    bool nact[3];
#pragma unroll
    for (int ni = 0; ni < 3; ++ni) {
        const int c = colbase + ni * 16 + r16;
        const int m = c >> 6;
        const int r = c & 63;
        wp[ni] = At + (size_t)((m * NS + s) * RMAX + r) * HID + k0 + kg * 8;
        nact[ni] = ((colbase + ni * 16) & 63) < rank;
    }

    f32x4 acc[3] = {};

#pragma unroll
    for (int ks = 0; ks < KCH / 32; ++ks) {
        const int kidx = ks * 32;
        const short8 af = *reinterpret_cast<const short8*>(xp + kidx);
#pragma unroll
        for (int ni = 0; ni < 3; ++ni) {
            if (!nact[ni]) continue;
            const short8 bf = *reinterpret_cast<const short8*>(wp[ni] + kidx);
            acc[ni] = __builtin_amdgcn_mfma_f32_16x16x32_bf16(af, bf, acc[ni], 0, 0, 0);
        }
    }

    // Epilogue: D layout col = lane&15, row = (lane>>4)*4 + j. Unconditional
    // stores (masked frags write zeros).
    float* slice = inter8 + (size_t)kc * INTER_ELEMS;
#pragma unroll
    for (int ni = 0; ni < 3; ++ni) {
        const int col = colbase + ni * 16 + r16;
#pragma unroll
        for (int j = 0; j < 4; ++j) {
            const int row = rowbase + kg * 4 + j;
            slice[(size_t)row * INTER_LD + col] = acc[ni][j];
        }
    }
}

// ---------------------------------------------------------------------------
// Kernel 3: reduce 8 f32 slices -> interb bf16. 672 blocks x 256 threads x
// 4 elems (float4 loads per slice, coalesced).
// ---------------------------------------------------------------------------
__global__ __launch_bounds__(256) void reduce_k(const float* __restrict__ inter8,
                                                unsigned short* __restrict__ interb) {
    const size_t idx = ((size_t)blockIdx.x * 256 + threadIdx.x) * 4;
    f32x4 s = {};
#pragma unroll
    for (int kc = 0; kc < KSPLIT; ++kc) {
        const float4 v = *reinterpret_cast<const float4*>(inter8 + (size_t)kc * INTER_ELEMS + idx);
        s[0] += v.x; s[1] += v.y; s[2] += v.z; s[3] += v.w;
    }
    union { unsigned short u[4]; uint2 d; } o;
#pragma unroll
    for (int j = 0; j < 4; ++j) o.u[j] = f2bf(s[j]);
    *reinterpret_cast<uint2*>(interb + idx) = o.d;
}

// ---------------------------------------------------------------------------
// Kernel 4: GEMM2  out[tok][m*2048+o] = sum_r interb[b][m*64+r] * Bt[ms][o][r]
// Grid: 1344 = 56 rowblocks(64) x 3 modules x 8 n-tiles(256).
// Block: 4 waves, wave = 64 rows x 64 cols, K = 64 (2 MFMA k-steps; second
// skipped when rank<=32). All-bf16 short8 loads.
// SWAPPED operands: mfma(bf, af) -> D transposed; lane holds one token row,
// 4 consecutive n-cols => float4 stores.
// ---------------------------------------------------------------------------
__global__ __launch_bounds__(256) void gemm2_k(const unsigned short* __restrict__ interb,
                                               const unsigned short* __restrict__ Bt,
                                               const int* __restrict__ sids,
                                               const int* __restrict__ slot_ranks,
                                               float* __restrict__ out) {
    const int bid = blockIdx.x;
    const int rb  = bid / 24;
    const int rem = bid - rb * 24;
    const int m   = rem >> 3;
    const int nt  = rem & 7;
    const int r0  = rb * 64;
    const int s   = slot_of_row(r0);
    const int rank = slot_ranks[s];
    const int ms  = m * NS + s;

    const int t    = threadIdx.x;
    const int w    = t >> 6;
    const int lane = t & 63;
    const int r16  = lane & 15;
    const int kg   = lane >> 4;
    const int n0   = nt * 256 + w * 64;

    int tok[4];
#pragma unroll
    for (int mi = 0; mi < 4; ++mi) tok[mi] = sids[r0 + mi * 16 + r16];

    const unsigned short* Bp = Bt + (size_t)ms * OUTD * RMAX;

    f32x4 acc[4][4] = {};

    const int nkk = (rank > 32) ? 2 : 1;
    for (int kk = 0; kk < nkk; ++kk) {
        const int kb = kk * 32 + kg * 8;
        short8 af[4];
#pragma unroll
        for (int mi = 0; mi < 4; ++mi)
            af[mi] = *reinterpret_cast<const short8*>(
                interb + (size_t)(r0 + mi * 16 + r16) * INTER_LD + m * RMAX + kb);
#pragma unroll
        for (int ni = 0; ni < 4; ++ni) {
            const short8 bf = *reinterpret_cast<const short8*>(
                Bp + (size_t)(n0 + ni * 16 + r16) * RMAX + kb);
#pragma unroll
            for (int mi = 0; mi < 4; ++mi)
                acc[mi][ni] = __builtin_amdgcn_mfma_f32_16x16x32_bf16(
                    bf, af[mi], acc[mi][ni], 0, 0, 0);   // swapped: D = tileT
        }
    }

    // Epilogue: lane r16 owns token row tok[mi]; cols n0+ni*16+kg*4..+3.
#pragma unroll
    for (int mi = 0; mi < 4; ++mi) {
        float* op = out + (size_t)tok[mi] * SUMOUT + m * OUTD + n0 + kg * 4;
#pragma unroll
        for (int ni = 0; ni < 4; ++ni) {
            float4 v;
            v.x = acc[mi][ni][0]; v.y = acc[mi][ni][1];
            v.z = acc[mi][ni][2]; v.w = acc[mi][ni][3];
            *reinterpret_cast<float4*>(op + ni * 16) = v;
        }
    }
}

// ---------------------------------------------------------------------------
extern "C" void kernel_launch(void* const* d_in, const int* in_sizes, int n_in,
                              void* d_out, int out_size, void* d_ws, size_t ws_size,
                              hipStream_t stream) {
    const float* x    = (const float*)d_in[0];
    const float* A    = (const float*)d_in[1];
    const float* B    = (const float*)d_in[2];
    const int* sids   = (const int*)d_in[3];
    // d_in[4] = row_slot (unused; slot boundaries are reference constants)
    const int* ranks  = (const int*)d_in[5];
    float* out        = (float*)d_out;

    char* ws = (char*)d_ws;
    float* inter8 = (float*)ws;                                   // 22.02 MB
    size_t off = (size_t)KSPLIT * INTER_ELEMS * sizeof(float);
    unsigned short* interb = (unsigned short*)(ws + off);         // 1.38 MB
    off += (size_t)INTER_ELEMS * sizeof(unsigned short);
    unsigned short* xg = (unsigned short*)(ws + off);             // 14.68 MB
    off += (size_t)NVALID * HID * sizeof(unsigned short);
    unsigned short* At = (unsigned short*)(ws + off);             // 3.15 MB
    off += (size_t)NM * NS * RMAX * HID * sizeof(unsigned short);
    unsigned short* Btp = (unsigned short*)(ws + off);            // 3.15 MB

    prep_k<<<dim3(2272), dim3(256), 0, stream>>>(x, sids, A, B, xg, At, Btp, out);
    gemm1_k<<<dim3(112 * 2 * KSPLIT), dim3(256), 0, stream>>>(xg, At, ranks, inter8);
    reduce_k<<<dim3(INTER_ELEMS / 1024), dim3(256), 0, stream>>>(inter8, interb);
    gemm2_k<<<dim3(1344), dim3(256), 0, stream>>>(interb, Btp, sids, ranks, out);
}